// Round 1
// baseline (4566.404 us; speedup 1.0000x reference)
//
#include <hip/hip_runtime.h>
#include <hip/hip_bf16.h>

#define WSZ 7
#define NH 4
#define HD 32
#define DIM 128
#define NTOK 49            // tokens per window
#define QKV_COLS 384
#define BLOCK 256

// One block per 7x7 window. LDS: xs (49x128 fp32, reused for attn-out),
// qkvs (49x384 bf16). Total 62,720 B -> 2 blocks/CU vs 160 KB pool.
__global__ __launch_bounds__(BLOCK, 2)
void win_attn_kernel(const float* __restrict__ x,
                     const float* __restrict__ w_qkv,
                     const float* __restrict__ b_qkv,
                     const float* __restrict__ w_proj,
                     const float* __restrict__ b_proj,
                     const float* __restrict__ bias_table,
                     float* __restrict__ out)
{
    __shared__ float xs[NTOK * DIM];                 // 25088 B; later attn-out
    __shared__ __hip_bfloat16 qkvs[NTOK * QKV_COLS]; // 37632 B

    const int tid = threadIdx.x;
    const int blk = blockIdx.x;
    const int b  = blk >> 12;        // / (64*64)
    const int wy = (blk >> 6) & 63;
    const int wx = blk & 63;

    const int imgBase = b * 448 * 448 * DIM;   // < 2^31, int is safe

    // ---- Phase 1: stage x window tile into LDS (float4 coalesced) ----
    for (int i = tid; i < NTOK * (DIM / 4); i += BLOCK) {
        const int tok = i >> 5;       // /32 float4 per token
        const int q4  = i & 31;
        const int r = tok / 7, c = tok % 7;
        const int gidx = imgBase + ((wy * 7 + r) * 448 + (wx * 7 + c)) * DIM + q4 * 4;
        *(float4*)(xs + tok * DIM + q4 * 4) = *(const float4*)(x + gidx);
    }
    __syncthreads();

    // ---- Phase 2: qkv = xs @ w_qkv + b_qkv -> bf16 in LDS ----
    // Thread owns one output column (waves 0..1 take a second pass: uniform).
    for (int c = tid; c < QKV_COLS; c += BLOCK) {
        float acc[NTOK];
        #pragma unroll
        for (int r = 0; r < NTOK; ++r) acc[r] = 0.f;
        for (int k0 = 0; k0 < DIM; k0 += 8) {
            float w[8];
            #pragma unroll
            for (int kk = 0; kk < 8; ++kk)
                w[kk] = w_qkv[(k0 + kk) * QKV_COLS + c];   // coalesced per k
            #pragma unroll
            for (int r = 0; r < NTOK; ++r) {
                const float4 xa = *(const float4*)(xs + r * DIM + k0);     // broadcast
                const float4 xb = *(const float4*)(xs + r * DIM + k0 + 4); // broadcast
                acc[r] += xa.x * w[0] + xa.y * w[1] + xa.z * w[2] + xa.w * w[3]
                        + xb.x * w[4] + xb.y * w[5] + xb.z * w[6] + xb.w * w[7];
            }
        }
        const float bias = b_qkv[c];
        #pragma unroll
        for (int r = 0; r < NTOK; ++r)
            qkvs[r * QKV_COLS + c] = __float2bfloat16(acc[r] + bias);
    }
    __syncthreads();

    // ---- Phase 3: per-(head,row) attention; writes attn-out into xs region ----
    if (tid < NH * NTOK) {
        const int h = tid / NTOK;     // 0..3
        const int r = tid % NTOK;     // 0..48
        const int qoff = h * HD;
        const int koff = DIM + h * HD;
        const int voff = 2 * DIM + h * HD;

        float qreg[HD];
        #pragma unroll
        for (int d = 0; d < HD; ++d)
            qreg[d] = __bfloat162float(qkvs[r * QKV_COLS + qoff + d]);

        const int ri = r / 7, ci = r % 7;
        const float scale = 0.17677669529663687f;  // 32^-0.5

        float s[NTOK];
        float m = -1e30f;
        #pragma unroll
        for (int j = 0; j < NTOK; ++j) {
            float dot = 0.f;
            #pragma unroll
            for (int d = 0; d < HD; ++d)
                dot += qreg[d] * __bfloat162float(qkvs[j * QKV_COLS + koff + d]);
            const int rj = j / 7, cj = j % 7;
            const float bias = bias_table[ri - rj + 6] + bias_table[ci - cj + 6];
            const float logit = dot * scale + bias;
            s[j] = logit;
            m = fmaxf(m, logit);
        }
        float sum = 0.f;
        #pragma unroll
        for (int j = 0; j < NTOK; ++j) { s[j] = __expf(s[j] - m); sum += s[j]; }
        const float inv = 1.f / sum;

        float o[HD];
        #pragma unroll
        for (int d = 0; d < HD; ++d) o[d] = 0.f;
        #pragma unroll
        for (int j = 0; j < NTOK; ++j) {
            const float p = s[j];
            #pragma unroll
            for (int d = 0; d < HD; ++d)
                o[d] += p * __bfloat162float(qkvs[j * QKV_COLS + voff + d]);
        }
        #pragma unroll
        for (int d = 0; d < HD; ++d)
            xs[r * DIM + qoff + d] = o[d] * inv;   // merged-head attn out
    }
    __syncthreads();

    // ---- Phase 4: out = attn_out @ w_proj + b_proj; write to global ----
    {
        const int c  = tid & 127;
        const int rg = tid >> 7;          // 0 or 1 (wave-uniform)
        const int r0 = rg * 24;           // rows 0..24 and 24..48 (row 24 dup, benign)
        float acc[25];
        #pragma unroll
        for (int r = 0; r < 25; ++r) acc[r] = 0.f;
        for (int k0 = 0; k0 < DIM; k0 += 8) {
            float w[8];
            #pragma unroll
            for (int kk = 0; kk < 8; ++kk)
                w[kk] = w_proj[(k0 + kk) * DIM + c];
            #pragma unroll
            for (int r = 0; r < 25; ++r) {
                const float4 xa = *(const float4*)(xs + (r0 + r) * DIM + k0);
                const float4 xb = *(const float4*)(xs + (r0 + r) * DIM + k0 + 4);
                acc[r] += xa.x * w[0] + xa.y * w[1] + xa.z * w[2] + xa.w * w[3]
                        + xb.x * w[4] + xb.y * w[5] + xb.z * w[6] + xb.w * w[7];
            }
        }
        const float bp = b_proj[c];
        #pragma unroll
        for (int r = 0; r < 25; ++r) {
            const int tok = r0 + r;
            const int ri = tok / 7, ci = tok % 7;
            out[imgBase + ((wy * 7 + ri) * 448 + (wx * 7 + ci)) * DIM + c] = acc[r] + bp;
        }
    }
}

extern "C" void kernel_launch(void* const* d_in, const int* in_sizes, int n_in,
                              void* d_out, int out_size, void* d_ws, size_t ws_size,
                              hipStream_t stream) {
    const float* x          = (const float*)d_in[0];
    const float* w_qkv      = (const float*)d_in[1];
    const float* b_qkv      = (const float*)d_in[2];
    const float* w_proj     = (const float*)d_in[3];
    const float* b_proj     = (const float*)d_in[4];
    const float* bias_table = (const float*)d_in[5];
    float* out = (float*)d_out;

    dim3 grid(16384), block(BLOCK);
    hipLaunchKernelGGL(win_attn_kernel, grid, block, 0, stream,
                       x, w_qkv, b_qkv, w_proj, b_proj, bias_table, out);
}

// Round 2
// 1205.654 us; speedup vs baseline: 3.7875x; 3.7875x over previous
//
#include <hip/hip_runtime.h>
#include <hip/hip_bf16.h>

#define NH 4
#define HD 32
#define DIM 128
#define NTOK 49
#define BLOCK 256

typedef __attribute__((ext_vector_type(8))) short short8;
typedef __attribute__((ext_vector_type(4))) float f32x4;

// strides in elements
#define XB_S 136   // bf16, 68 dw % 32 = 4 -> 2-way (free)
#define QK_S 264   // bf16, 132 dw % 32 = 4
#define VT_S 72    // bf16, 36 dw % 32 = 4
#define S_S  68    // f32,  68 dw % 32 = 4
#define P_S  72    // bf16

// LDS byte offsets (all 16-aligned)
#define OFF_XB   0          // xb 49*136*2 = 13,328 ; aliased later by S slabs 4*4352=17,408
#define OFF_QK   17408      // qk 49*264*2 = 25,872 ; aliased later by ao(13,328)+P(9,216)
#define OFF_AO   17408
#define OFF_P    30736      // 4 slabs * 2304
#define OFF_VT   43280      // vts 128*72*2 = 18,432
#define OFF_BT   61712      // bias table 13 f32
#define SMEM_SZ  61776

__device__ __forceinline__ short f2bf(float f) {
    union { float f; unsigned u; } v; v.f = f;
    unsigned r = (v.u + 0x7FFFu + ((v.u >> 16) & 1u)) >> 16;
    return (short)r;
}

// Pre-swizzle weights into MFMA B-fragment order: [nt][kt][lane][8] bf16.
// B-frag (16x16x32): lane l holds B[k = kt*32 + (l>>4)*8 + j][n = nt*16 + (l&15)].
__global__ void prep_kernel(const float* __restrict__ wq,
                            const float* __restrict__ wp,
                            short* __restrict__ ws) {
    int t = blockIdx.x * 256 + threadIdx.x;   // 65,536 total
    if (t < 49152) {                           // w_qkv: 24 nt * 4 kt * 64 * 8
        int j = t & 7, lane = (t >> 3) & 63, kt = (t >> 9) & 3, nt = t >> 11;
        int n = nt * 16 + (lane & 15);
        int k = kt * 32 + (lane >> 4) * 8 + j;
        ws[t] = f2bf(wq[k * 384 + n]);
    } else {
        int u = t - 49152;                     // w_proj: 8 nt * 4 kt * 64 * 8
        int j = u & 7, lane = (u >> 3) & 63, kt = (u >> 9) & 3, nt = u >> 11;
        int n = nt * 16 + (lane & 15);
        int k = kt * 32 + (lane >> 4) * 8 + j;
        ws[t] = f2bf(wp[k * 128 + n]);
    }
}

__global__ __launch_bounds__(BLOCK, 2)
void win_attn_kernel(const float* __restrict__ x,
                     const float* __restrict__ b_qkv,
                     const float* __restrict__ b_proj,
                     const float* __restrict__ bias_table,
                     const short* __restrict__ ws,     // swizzled weights
                     float* __restrict__ out)
{
    __shared__ __align__(16) char smem[SMEM_SZ];
    short* xb = (short*)(smem + OFF_XB);
    short* qk = (short*)(smem + OFF_QK);
    short* ao = (short*)(smem + OFF_AO);
    short* vt = (short*)(smem + OFF_VT);
    float* bt = (float*)(smem + OFF_BT);

    const int tid = threadIdx.x;
    const int w   = tid >> 6;        // wave id (0..3)
    const int l   = tid & 63;        // lane
    const int lm  = l & 15;
    const int q4  = l >> 4;          // quad

    const int blk = blockIdx.x;
    const int b  = blk >> 12;
    const int wy = (blk >> 6) & 63;
    const int wx = blk & 63;
    const int imgBase = b * 448 * 448 * DIM;

    const short* wqkv_ws  = ws;
    const short* wproj_ws = ws + 49152;

    // ---------------- Phase 1: stage x -> xb (bf16), zero vt pad, bias table ----
    for (int i = tid; i < NTOK * 32; i += BLOCK) {
        const int tok = i >> 5;
        const int c4  = i & 31;
        const int r = tok / 7, c = tok % 7;
        const float4 v = *(const float4*)(x + imgBase + ((wy*7 + r)*448 + (wx*7 + c))*DIM + c4*4);
        short4 s4;
        s4.x = f2bf(v.x); s4.y = f2bf(v.y); s4.z = f2bf(v.z); s4.w = f2bf(v.w);
        *(short4*)(xb + tok * XB_S + c4 * 4) = s4;
    }
    {   // zero V^T pad cols (tok 48..63); tok 48 rewritten by phase 2
        const int vcol = tid >> 1;
        const int t0 = 48 + (tid & 1) * 8;
        short8 z = {0,0,0,0,0,0,0,0};
        *(short8*)(vt + vcol * VT_S + t0) = z;
    }
    if (tid < 13) bt[tid] = bias_table[tid];
    __syncthreads();   // b0

    // ---------------- Phase 2: QKV GEMM (49x128 @ 128x384) -----------------
    {
        short8 af[4][4];   // [mt][kt] A-frags from xb
        #pragma unroll
        for (int mt = 0; mt < 4; ++mt) {
            int row = 16*mt + lm; if (row > 48) row = 48;
            #pragma unroll
            for (int kt = 0; kt < 4; ++kt)
                af[mt][kt] = *(const short8*)(xb + row * XB_S + kt*32 + q4*8);
        }
        short8 bf[2][4];
        {   const int nt0 = w * 6;
            #pragma unroll
            for (int kt = 0; kt < 4; ++kt)
                bf[0][kt] = *(const short8*)(wqkv_ws + ((nt0*4 + kt)*64 + l)*8);
        }
        #pragma unroll
        for (int t = 0; t < 6; ++t) {
            const int nt = w * 6 + t;
            if (t < 5) {
                const int ntn = nt + 1;
                #pragma unroll
                for (int kt = 0; kt < 4; ++kt)
                    bf[(t+1)&1][kt] = *(const short8*)(wqkv_ws + ((ntn*4 + kt)*64 + l)*8);
            }
            const int col = nt * 16 + lm;
            const float bq = b_qkv[col];
            f32x4 acc[4] = { {0,0,0,0},{0,0,0,0},{0,0,0,0},{0,0,0,0} };
            #pragma unroll
            for (int kt = 0; kt < 4; ++kt) {
                #pragma unroll
                for (int mt = 0; mt < 4; ++mt)
                    acc[mt] = __builtin_amdgcn_mfma_f32_16x16x32_bf16(
                                  af[mt][kt], bf[t&1][kt], acc[mt], 0, 0, 0);
            }
            const bool isV = (col >= 256);   // wave-uniform per nt
            #pragma unroll
            for (int mt = 0; mt < 4; ++mt) {
                #pragma unroll
                for (int r = 0; r < 4; ++r) {
                    const int row = 16*mt + q4*4 + r;
                    if (row < NTOK) {
                        const short bv = f2bf(acc[mt][r] + bq);
                        if (isV) vt[(col - 256) * VT_S + row] = bv;
                        else     qk[row * QK_S + col] = bv;
                    }
                }
            }
        }
    }
    __syncthreads();   // b1

    // ---------------- Phase 3: attention, wave = head ------------------------
    {
        const int h = w;
        short8 qf[4], kf[4], vf[2][2];
        #pragma unroll
        for (int mt = 0; mt < 4; ++mt) {
            int row = 16*mt + lm; if (row > 48) row = 48;
            qf[mt] = *(const short8*)(qk + row * QK_S + 32*h + q4*8);
        }
        #pragma unroll
        for (int nt = 0; nt < 4; ++nt) {
            int row = 16*nt + lm; if (row > 48) row = 48;
            kf[nt] = *(const short8*)(qk + row * QK_S + 128 + 32*h + q4*8);
        }
        #pragma unroll
        for (int n2 = 0; n2 < 2; ++n2)
            #pragma unroll
            for (int k2 = 0; k2 < 2; ++k2)
                vf[n2][k2] = *(const short8*)(vt + (32*h + 16*n2 + lm) * VT_S + k2*32 + q4*8);
        __syncthreads();   // b2 — qk/ao aliasing safe after this

        float* s_slab = (float*)(smem + OFF_XB) + h * (16 * S_S);      // aliases xb
        short* p_slab = (short*)(smem + OFF_P)  + h * (16 * P_S);
        const float scale = 0.17677669529663687f;

        for (int mt = 0; mt < 4; ++mt) {
            f32x4 sacc[4];
            #pragma unroll
            for (int nt = 0; nt < 4; ++nt)
                sacc[nt] = __builtin_amdgcn_mfma_f32_16x16x32_bf16(
                               qf[mt], kf[nt], (f32x4){0,0,0,0}, 0, 0, 0);
            #pragma unroll
            for (int nt = 0; nt < 4; ++nt)
                #pragma unroll
                for (int r = 0; r < 4; ++r)
                    s_slab[(q4*4 + r) * S_S + nt*16 + lm] = sacc[nt][r];
            __syncthreads();

            // softmax: row = lm (16 rows), 4 lanes (q4) split the 49 cols
            const int rg = 16*mt + lm;
            const int j0 = (q4 < 3) ? q4 * 13 : 39;
            const int jn = (q4 < 3) ? 13 : 10;
            float logit[13];
            float mval = -1e30f;
            if (rg < NTOK) {
                const int ri = rg / 7, ci = rg % 7;
                int rj = j0 / 7, cj = j0 % 7;
                for (int u = 0; u < jn; ++u) {
                    const float lv = s_slab[lm * S_S + (j0 + u)] * scale
                                   + bt[ri - rj + 6] + bt[ci - cj + 6];
                    logit[u] = lv;
                    mval = fmaxf(mval, lv);
                    if (++cj == 7) { cj = 0; ++rj; }
                }
            }
            mval = fmaxf(mval, __shfl_xor(mval, 16, 64));
            mval = fmaxf(mval, __shfl_xor(mval, 32, 64));
            float sum = 0.f;
            if (rg < NTOK) {
                for (int u = 0; u < jn; ++u) {
                    const float e = __expf(logit[u] - mval);
                    logit[u] = e; sum += e;
                }
            }
            sum += __shfl_xor(sum, 16, 64);
            sum += __shfl_xor(sum, 32, 64);
            if (rg < NTOK) {
                const float inv = 1.f / sum;
                for (int u = 0; u < jn; ++u)
                    p_slab[lm * P_S + (j0 + u)] = f2bf(logit[u] * inv);
                for (int j = 49 + q4; j < 64; j += 4)
                    p_slab[lm * P_S + j] = 0;
            }
            __syncthreads();

            // PV: O(16x32) += P(16x64) @ V(64x32)
            short8 pf[2];
            #pragma unroll
            for (int k2 = 0; k2 < 2; ++k2)
                pf[k2] = *(const short8*)(p_slab + lm * P_S + k2*32 + q4*8);
            f32x4 oacc[2] = { {0,0,0,0},{0,0,0,0} };
            #pragma unroll
            for (int n2 = 0; n2 < 2; ++n2)
                #pragma unroll
                for (int k2 = 0; k2 < 2; ++k2)
                    oacc[n2] = __builtin_amdgcn_mfma_f32_16x16x32_bf16(
                                   pf[k2], vf[n2][k2], oacc[n2], 0, 0, 0);
            #pragma unroll
            for (int n2 = 0; n2 < 2; ++n2)
                #pragma unroll
                for (int r = 0; r < 4; ++r) {
                    const int row = 16*mt + q4*4 + r;
                    if (row < NTOK)
                        ao[row * XB_S + 32*h + 16*n2 + lm] = f2bf(oacc[n2][r]);
                }
            __syncthreads();
        }
    }
    __syncthreads();   // b3: all attn-out written

    // ---------------- Phase 4: out proj (49x128 @ 128x128) -------------------
    {
        short8 af[4][4];
        #pragma unroll
        for (int mt = 0; mt < 4; ++mt) {
            int row = 16*mt + lm; if (row > 48) row = 48;
            #pragma unroll
            for (int kt = 0; kt < 4; ++kt)
                af[mt][kt] = *(const short8*)(ao + row * XB_S + kt*32 + q4*8);
        }
        #pragma unroll
        for (int t = 0; t < 2; ++t) {
            const int nt = w * 2 + t;
            short8 bf[4];
            #pragma unroll
            for (int kt = 0; kt < 4; ++kt)
                bf[kt] = *(const short8*)(wproj_ws + ((nt*4 + kt)*64 + l)*8);
            const int col = nt * 16 + lm;
            const float bp = b_proj[col];
            f32x4 acc[4] = { {0,0,0,0},{0,0,0,0},{0,0,0,0},{0,0,0,0} };
            #pragma unroll
            for (int kt = 0; kt < 4; ++kt)
                #pragma unroll
                for (int mt = 0; mt < 4; ++mt)
                    acc[mt] = __builtin_amdgcn_mfma_f32_16x16x32_bf16(
                                  af[mt][kt], bf[kt], acc[mt], 0, 0, 0);
            #pragma unroll
            for (int mt = 0; mt < 4; ++mt)
                #pragma unroll
                for (int r = 0; r < 4; ++r) {
                    const int row = 16*mt + q4*4 + r;
                    if (row < NTOK) {
                        const int tr = row / 7, tc = row % 7;
                        out[imgBase + ((wy*7 + tr)*448 + (wx*7 + tc))*DIM + col]
                            = acc[mt][r] + bp;
                    }
                }
        }
    }
}

extern "C" void kernel_launch(void* const* d_in, const int* in_sizes, int n_in,
                              void* d_out, int out_size, void* d_ws, size_t ws_size,
                              hipStream_t stream) {
    const float* x          = (const float*)d_in[0];
    const float* w_qkv      = (const float*)d_in[1];
    const float* b_qkv      = (const float*)d_in[2];
    const float* w_proj     = (const float*)d_in[3];
    const float* b_proj     = (const float*)d_in[4];
    const float* bias_table = (const float*)d_in[5];
    float* out = (float*)d_out;
    short* ws  = (short*)d_ws;

    hipLaunchKernelGGL(prep_kernel, dim3(256), dim3(256), 0, stream,
                       w_qkv, w_proj, ws);
    hipLaunchKernelGGL(win_attn_kernel, dim3(16384), dim3(BLOCK), 0, stream,
                       x, b_qkv, b_proj, bias_table, ws, out);
}